// Round 5
// baseline (366.940 us; speedup 1.0000x reference)
//
#include <hip/hip_runtime.h>
#include <hip/hip_bf16.h>

// Problem constants (fixed by the reference)
#define N_ROWS 262144
#define IN_DIM 128
#define OUT_DIM 128
#define NTYPES 8
#define ROWS_PER_BLOCK 128  // 2048 blocks = 8 blocks/CU -> 32 waves/CU target
#define GROUP_M 32          // rows per group: two 16-row MFMA tiles sharing B
#define MAX_GROUPS 16       // sum ceil(c_t/32) <= 11 for 128 rows / 8 types

typedef short bf16x8 __attribute__((ext_vector_type(8)));   // 8 bf16 in 4 VGPRs
typedef float f32x4 __attribute__((ext_vector_type(4)));    // plain vector: ok for nontemporal builtins

__device__ __forceinline__ unsigned short f2bf_rne(float f) {
    unsigned int u = __float_as_uint(f);
    u += 0x7fff + ((u >> 16) & 1);   // round-nearest-even; inputs finite/normal
    return (unsigned short)(u >> 16);
}

// W [T][IN][OUT] fp32 -> Wb [T][OUT][IN] bf16. 1024 blocks x 128 threads:
// block (t,o), lane i: strided 4B reads (W is 512KB, L2/L3-resident), 2B
// contiguous writes. Wide grid so this kernel is ~2us.
__global__ void __launch_bounds__(128) prep_w_kernel(const float* __restrict__ W,
                                                     unsigned short* __restrict__ Wb) {
    const int t = blockIdx.x >> 7;
    const int o = blockIdx.x & 127;
    const int i = threadIdx.x;
    Wb[(t * OUT_DIM + o) * IN_DIM + i] = f2bf_rne(W[(t * IN_DIM + i) * OUT_DIM + o]);
}

__device__ __forceinline__ bf16x8 cvt_8f32_to_bf16(f32x4 f0, f32x4 f1) {
    union { bf16x8 v; __hip_bfloat162 h[4]; } u;
    u.h[0] = __float22bfloat162_rn(make_float2(f0[0], f0[1]));
    u.h[1] = __float22bfloat162_rn(make_float2(f0[2], f0[3]));
    u.h[2] = __float22bfloat162_rn(make_float2(f1[0], f1[1]));
    u.h[3] = __float22bfloat162_rn(make_float2(f1[2], f1[3]));
    return u.v;
}

// launch_bounds(256, 8): 8 waves/EU -> 8 blocks/CU; forces VGPR <= 64 so the
// grid (2048 blocks / 256 CU) can actually reach 32 waves/CU. r4 counters
// showed the latency-bound signature (Mfma 3.5%, VALU 6.6%, HBM 24%, occ 35%)
// with occupancy grid-capped at 4 blocks/CU.
__global__ void __launch_bounds__(256, 8) typed_linear_kernel(
        const float* __restrict__ x, const int* __restrict__ xt,
        const unsigned short* __restrict__ Wb, const float* __restrict__ bias,
        float* __restrict__ out) {
    __shared__ int s_cnt[NTYPES];
    __shared__ int s_cursor[NTYPES];
    __shared__ unsigned short s_list[ROWS_PER_BLOCK];
    __shared__ unsigned char s_gtype[MAX_GROUPS];
    __shared__ short s_gstart[MAX_GROUPS];
    __shared__ unsigned char s_gcnt[MAX_GROUPS];
    __shared__ int s_ngroups;
    __shared__ float s_bias[NTYPES * OUT_DIM];   // 4 KB

    const int tid = threadIdx.x;
    const int row0 = blockIdx.x * ROWS_PER_BLOCK;

    // ---- Phase 1: bucket this block's 128 rows by type ----
    if (tid < NTYPES) s_cnt[tid] = 0;
    __syncthreads();
    int my_t = -1;
    if (tid < ROWS_PER_BLOCK) {
        my_t = xt[row0 + tid];
        atomicAdd(&s_cnt[my_t], 1);
    }
    // Stage all biases to LDS (8*128 floats, 256 threads x float4, coalesced).
    reinterpret_cast<float4*>(s_bias)[tid] = reinterpret_cast<const float4*>(bias)[tid];
    __syncthreads();
    if (tid == 0) {
        int acc = 0, g = 0;
        for (int i = 0; i < NTYPES; ++i) {
            int c = s_cnt[i];
            s_cursor[i] = acc;
            for (int s = 0; s < c; s += GROUP_M) {
                s_gtype[g] = (unsigned char)i;
                s_gstart[g] = (short)(acc + s);
                s_gcnt[g] = (unsigned char)((c - s) < GROUP_M ? (c - s) : GROUP_M);
                ++g;
            }
            acc += c;
        }
        s_ngroups = g;
    }
    __syncthreads();
    if (tid < ROWS_PER_BLOCK) {
        int pos = atomicAdd(&s_cursor[my_t], 1);
        s_list[pos] = (unsigned short)tid;
    }
    __syncthreads();

    // ---- Phase 2: per-wave direct-to-register MFMA over 32-row groups ----
    const int wave = tid >> 6;
    const int lane = tid & 63;
    const int m = lane & 15;     // A row / B col / C col within 16-tile
    const int q = lane >> 4;     // quad: A k-chunk = q*8.., C rows = q*4..q*4+3
    const int ngroups = s_ngroups;

    for (int g = wave; g < ngroups; g += 4) {
        const int t  = s_gtype[g];
        const int gs = s_gstart[g];
        const int gc = s_gcnt[g];
        const bool two = (gc > 16);   // wave-uniform: second 16-row tile live?

        // A source rows (clamp padded rows; duplicate reads hit L1).
        const int mm0 = (m < gc) ? m : (gc - 1);
        const float* ap0 = x + (size_t)(row0 + s_list[gs + mm0]) * IN_DIM + q * 8;

        bf16x8 afrag[2][4];
        #pragma unroll
        for (int kc = 0; kc < 4; ++kc) {
            const f32x4 f0 = __builtin_nontemporal_load(
                reinterpret_cast<const f32x4*>(ap0 + kc * 32));
            const f32x4 f1 = __builtin_nontemporal_load(
                reinterpret_cast<const f32x4*>(ap0 + kc * 32 + 4));
            afrag[0][kc] = cvt_8f32_to_bf16(f0, f1);
        }
        if (two) {
            const int r1 = 16 + m;
            const int mm1 = (r1 < gc) ? r1 : (gc - 1);
            const float* ap1 = x + (size_t)(row0 + s_list[gs + mm1]) * IN_DIM + q * 8;
            #pragma unroll
            for (int kc = 0; kc < 4; ++kc) {
                const f32x4 f0 = __builtin_nontemporal_load(
                    reinterpret_cast<const f32x4*>(ap1 + kc * 32));
                const f32x4 f1 = __builtin_nontemporal_load(
                    reinterpret_cast<const f32x4*>(ap1 + kc * 32 + 4));
                afrag[1][kc] = cvt_8f32_to_bf16(f0, f1);
            }
        }

        // Output rows this lane stores (C layout: row = q*4+r, col = m)
        int orow0[4], orow1[4];
        #pragma unroll
        for (int r = 0; r < 4; ++r) {
            const int mr0 = q * 4 + r;
            orow0[r] = (mr0 < gc) ? (row0 + s_list[gs + mr0]) : -1;
            const int mr1 = 16 + q * 4 + r;
            orow1[r] = (mr1 < gc) ? (row0 + s_list[gs + mr1]) : -1;
        }

        const unsigned short* wt = Wb + t * (IN_DIM * OUT_DIM);
        const float* sb = s_bias + t * OUT_DIM;

        // 8 output-col tiles; each B-fragment set feeds both row-tiles.
        if (two) {
            #pragma unroll
            for (int nt = 0; nt < 8; ++nt) {
                const unsigned short* wcol = wt + (nt * 16 + m) * IN_DIM + q * 8;
                bf16x8 bfr[4];
                #pragma unroll
                for (int kc = 0; kc < 4; ++kc)
                    bfr[kc] = *reinterpret_cast<const bf16x8*>(wcol + kc * 32);
                f32x4 acc0 = {0.f, 0.f, 0.f, 0.f};
                f32x4 acc1 = {0.f, 0.f, 0.f, 0.f};
                #pragma unroll
                for (int kc = 0; kc < 4; ++kc) {
                    acc0 = __builtin_amdgcn_mfma_f32_16x16x32_bf16(afrag[0][kc], bfr[kc], acc0, 0, 0, 0);
                    acc1 = __builtin_amdgcn_mfma_f32_16x16x32_bf16(afrag[1][kc], bfr[kc], acc1, 0, 0, 0);
                }
                const float bv = sb[nt * 16 + m];
                #pragma unroll
                for (int r = 0; r < 4; ++r) {
                    if (orow0[r] >= 0)
                        __builtin_nontemporal_store(acc0[r] + bv,
                            &out[(size_t)orow0[r] * OUT_DIM + nt * 16 + m]);
                    if (orow1[r] >= 0)
                        __builtin_nontemporal_store(acc1[r] + bv,
                            &out[(size_t)orow1[r] * OUT_DIM + nt * 16 + m]);
                }
            }
        } else {
            #pragma unroll
            for (int nt = 0; nt < 8; ++nt) {
                const unsigned short* wcol = wt + (nt * 16 + m) * IN_DIM + q * 8;
                bf16x8 bfr[4];
                #pragma unroll
                for (int kc = 0; kc < 4; ++kc)
                    bfr[kc] = *reinterpret_cast<const bf16x8*>(wcol + kc * 32);
                f32x4 acc0 = {0.f, 0.f, 0.f, 0.f};
                #pragma unroll
                for (int kc = 0; kc < 4; ++kc)
                    acc0 = __builtin_amdgcn_mfma_f32_16x16x32_bf16(afrag[0][kc], bfr[kc], acc0, 0, 0, 0);
                const float bv = sb[nt * 16 + m];
                #pragma unroll
                for (int r = 0; r < 4; ++r) {
                    if (orow0[r] >= 0)
                        __builtin_nontemporal_store(acc0[r] + bv,
                            &out[(size_t)orow0[r] * OUT_DIM + nt * 16 + m]);
                }
            }
        }
    }
}

extern "C" void kernel_launch(void* const* d_in, const int* in_sizes, int n_in,
                              void* d_out, int out_size, void* d_ws, size_t ws_size,
                              hipStream_t stream) {
    const float* x  = (const float*)d_in[0];
    const int* xt   = (const int*)d_in[1];
    const float* W  = (const float*)d_in[2];
    const float* b  = (const float*)d_in[3];
    float* out      = (float*)d_out;
    unsigned short* Wb = (unsigned short*)d_ws;   // 8*128*128*2 = 256 KiB scratch

    prep_w_kernel<<<NTYPES * OUT_DIM, 128, 0, stream>>>(W, Wb);
    typed_linear_kernel<<<N_ROWS / ROWS_PER_BLOCK, 256, 0, stream>>>(x, xt, Wb, b, out);
}

// Round 6
// 315.649 us; speedup vs baseline: 1.1625x; 1.1625x over previous
//
#include <hip/hip_runtime.h>
#include <hip/hip_bf16.h>

// Problem constants (fixed by the reference)
#define N_ROWS 262144
#define IN_DIM 128
#define OUT_DIM 128
#define NTYPES 8
#define ROWS_PER_BLOCK 256  // 1024 blocks = 4 blocks/CU (proven r4 config)
#define GROUP_M 16          // one 16x128 C-tile per group; acc[8] persisted
#define MAX_GROUPS 32       // sum ceil(c_t/16) <= 23 for 256 rows / 8 types
#define ROW_PAD 132         // LDS epilogue row stride (floats): 2-way max aliasing

typedef short bf16x8 __attribute__((ext_vector_type(8)));   // 8 bf16 in 4 VGPRs
typedef float f32x4 __attribute__((ext_vector_type(4)));

__device__ __forceinline__ unsigned short f2bf_rne(float f) {
    unsigned int u = __float_as_uint(f);
    u += 0x7fff + ((u >> 16) & 1);   // round-nearest-even; inputs finite/normal
    return (unsigned short)(u >> 16);
}

// W [T][IN][OUT] fp32 -> Wb [T][OUT][IN] bf16. 1024 blocks x 128 threads.
__global__ void __launch_bounds__(128) prep_w_kernel(const float* __restrict__ W,
                                                     unsigned short* __restrict__ Wb) {
    const int t = blockIdx.x >> 7;
    const int o = blockIdx.x & 127;
    const int i = threadIdx.x;
    Wb[(t * OUT_DIM + o) * IN_DIM + i] = f2bf_rne(W[(t * IN_DIM + i) * OUT_DIM + o]);
}

__device__ __forceinline__ bf16x8 cvt_8f32_to_bf16(f32x4 f0, f32x4 f1) {
    union { bf16x8 v; __hip_bfloat162 h[4]; } u;
    u.h[0] = __float22bfloat162_rn(make_float2(f0[0], f0[1]));
    u.h[1] = __float22bfloat162_rn(make_float2(f0[2], f0[3]));
    u.h[2] = __float22bfloat162_rn(make_float2(f1[0], f1[1]));
    u.h[3] = __float22bfloat162_rn(make_float2(f1[2], f1[3]));
    return u.v;
}

// r5 post-mortem: scattered per-nt 64B half-line stores caused 2.1x FETCH+WRITE
// amplification (half-dirty 128B lines evicted then re-fetched to merge).
// Fix: persist acc[8] across the nt loop, transpose the 16x128 C-tile through
// wave-private LDS, store full 512B-contiguous rows (dwordx4, 2 rows/instr).
__global__ void __launch_bounds__(256, 4) typed_linear_kernel(
        const float* __restrict__ x, const int* __restrict__ xt,
        const unsigned short* __restrict__ Wb, const float* __restrict__ bias,
        float* __restrict__ out) {
    __shared__ float s_out[4][GROUP_M * ROW_PAD];   // 4 waves x 8448 B = 33 KB
    __shared__ int s_cnt[NTYPES];
    __shared__ int s_cursor[NTYPES];
    __shared__ unsigned short s_list[ROWS_PER_BLOCK];
    __shared__ unsigned char s_gtype[MAX_GROUPS];
    __shared__ short s_gstart[MAX_GROUPS];
    __shared__ unsigned char s_gcnt[MAX_GROUPS];
    __shared__ int s_ngroups;
    __shared__ float s_bias[NTYPES * OUT_DIM];   // 4 KB

    const int tid = threadIdx.x;
    const int row0 = blockIdx.x * ROWS_PER_BLOCK;

    // ---- Phase 1: bucket this block's 256 rows by type ----
    if (tid < NTYPES) s_cnt[tid] = 0;
    __syncthreads();
    const int my_t = xt[row0 + tid];
    atomicAdd(&s_cnt[my_t], 1);
    // Stage all biases to LDS (8*128 floats = 256 float4, one per thread).
    reinterpret_cast<float4*>(s_bias)[tid] = reinterpret_cast<const float4*>(bias)[tid];
    __syncthreads();
    if (tid == 0) {
        int acc = 0, g = 0;
        for (int i = 0; i < NTYPES; ++i) {
            int c = s_cnt[i];
            s_cursor[i] = acc;
            for (int s = 0; s < c; s += GROUP_M) {
                s_gtype[g] = (unsigned char)i;
                s_gstart[g] = (short)(acc + s);
                s_gcnt[g] = (unsigned char)((c - s) < GROUP_M ? (c - s) : GROUP_M);
                ++g;
            }
            acc += c;
        }
        s_ngroups = g;
    }
    __syncthreads();
    {
        int pos = atomicAdd(&s_cursor[my_t], 1);
        s_list[pos] = (unsigned short)tid;
    }
    __syncthreads();

    // ---- Phase 2: per-wave MFMA over 16-row groups, LDS-transposed stores ----
    const int wave = tid >> 6;
    const int lane = tid & 63;
    const int m = lane & 15;     // A row / B col / C col within 16-tile
    const int q = lane >> 4;     // quad: A k-chunk = q*8.., C rows = q*4..q*4+3
    const int ngroups = s_ngroups;
    float* sow = s_out[wave];

    for (int g = wave; g < ngroups; g += 4) {
        const int t  = s_gtype[g];
        const int gs = s_gstart[g];
        const int gc = s_gcnt[g];

        // A fragments: lane (m,q) reads row m floats [kc*32+q*8, +8).
        // Per load instruction the wave covers 16 rows x contiguous segments.
        const int mm0 = (m < gc) ? m : (gc - 1);   // clamp padded rows (L1 hit)
        const float* ap0 = x + (size_t)(row0 + s_list[gs + mm0]) * IN_DIM + q * 8;
        bf16x8 afrag[4];
        #pragma unroll
        for (int kc = 0; kc < 4; ++kc) {
            const f32x4 f0 = *reinterpret_cast<const f32x4*>(ap0 + kc * 32);
            const f32x4 f1 = *reinterpret_cast<const f32x4*>(ap0 + kc * 32 + 4);
            afrag[kc] = cvt_8f32_to_bf16(f0, f1);
        }

        const unsigned short* wt = Wb + t * (IN_DIM * OUT_DIM);
        const float* sb = s_bias + t * OUT_DIM;

        // Main loop: 8 output-col tiles, acc persisted (32 VGPRs), no stores
        // interleaved -> compiler free to pipeline B loads across nt.
        f32x4 acc[8];
        #pragma unroll
        for (int nt = 0; nt < 8; ++nt) {
            const unsigned short* wcol = wt + (nt * 16 + m) * IN_DIM + q * 8;
            bf16x8 bfr[4];
            #pragma unroll
            for (int kc = 0; kc < 4; ++kc)
                bfr[kc] = *reinterpret_cast<const bf16x8*>(wcol + kc * 32);
            f32x4 a = {0.f, 0.f, 0.f, 0.f};
            #pragma unroll
            for (int kc = 0; kc < 4; ++kc)
                a = __builtin_amdgcn_mfma_f32_16x16x32_bf16(afrag[kc], bfr[kc], a, 0, 0, 0);
            acc[nt] = a;
        }

        // Epilogue A: transpose C + bias into wave-private LDS.
        // Write (nt,r): rows q*4+r stride ROW_PAD -> banks differ by (q*16+4r)%32
        // across q: 2-way max (free).
        #pragma unroll
        for (int nt = 0; nt < 8; ++nt) {
            const float bv = sb[nt * 16 + m];
            #pragma unroll
            for (int r = 0; r < 4; ++r)
                sow[(q * 4 + r) * ROW_PAD + nt * 16 + m] = acc[nt][r] + bv;
        }

        // Epilogue B: read back row-major, store full 512B-contiguous rows.
        // Wave-private buffer -> no barrier; compiler orders via lgkmcnt.
        const int half = lane >> 5;      // 2 rows per store instruction
        const int c4 = (lane & 31) * 4;  // float col within row
        #pragma unroll
        for (int j = 0; j < 8; ++j) {
            const int rr = j * 2 + half;
            if (rr < gc) {
                const int orow = row0 + s_list[gs + rr];
                const f32x4 v = *reinterpret_cast<const f32x4*>(&sow[rr * ROW_PAD + c4]);
                *reinterpret_cast<f32x4*>(&out[(size_t)orow * OUT_DIM + c4]) = v;
            }
        }
    }
}

extern "C" void kernel_launch(void* const* d_in, const int* in_sizes, int n_in,
                              void* d_out, int out_size, void* d_ws, size_t ws_size,
                              hipStream_t stream) {
    const float* x  = (const float*)d_in[0];
    const int* xt   = (const int*)d_in[1];
    const float* W  = (const float*)d_in[2];
    const float* b  = (const float*)d_in[3];
    float* out      = (float*)d_out;
    unsigned short* Wb = (unsigned short*)d_ws;   // 8*128*128*2 = 256 KiB scratch

    prep_w_kernel<<<NTYPES * OUT_DIM, 128, 0, stream>>>(W, Wb);
    typed_linear_kernel<<<N_ROWS / ROWS_PER_BLOCK, 256, 0, stream>>>(x, xt, Wb, b, out);
}

// Round 7
// 293.331 us; speedup vs baseline: 1.2509x; 1.0761x over previous
//
#include <hip/hip_runtime.h>
#include <hip/hip_bf16.h>

// Problem constants (fixed by the reference)
#define N_ROWS 262144
#define IN_DIM 128
#define OUT_DIM 128
#define NTYPES 8
#define ROWS_PER_BLOCK 256  // 1024 blocks = 4 blocks/CU
#define GROUP_M 16          // one 16x128 C-tile per group; acc[8] persisted
#define MAX_GROUPS 32       // sum ceil(c_t/16) <= 23 for 256 rows / 8 types
#define ROW_PAD 132         // LDS epilogue row stride (floats): 2-way max aliasing

typedef short bf16x8 __attribute__((ext_vector_type(8)));   // 8 bf16 in 4 VGPRs
typedef float f32x4 __attribute__((ext_vector_type(4)));

__device__ __forceinline__ unsigned short f2bf_rne(float f) {
    unsigned int u = __float_as_uint(f);
    u += 0x7fff + ((u >> 16) & 1);   // round-nearest-even; inputs finite/normal
    return (unsigned short)(u >> 16);
}

// W [T][IN][OUT] fp32 -> Wb [T][OUT][IN] bf16. 1024 blocks x 128 threads.
__global__ void __launch_bounds__(128) prep_w_kernel(const float* __restrict__ W,
                                                     unsigned short* __restrict__ Wb) {
    const int t = blockIdx.x >> 7;
    const int o = blockIdx.x & 127;
    const int i = threadIdx.x;
    Wb[(t * OUT_DIM + o) * IN_DIM + i] = f2bf_rne(W[(t * IN_DIM + i) * OUT_DIM + o]);
}

__device__ __forceinline__ bf16x8 cvt_8f32_to_bf16(f32x4 f0, f32x4 f1) {
    union { bf16x8 v; __hip_bfloat162 h[4]; } u;
    u.h[0] = __float22bfloat162_rn(make_float2(f0[0], f0[1]));
    u.h[1] = __float22bfloat162_rn(make_float2(f0[2], f0[3]));
    u.h[2] = __float22bfloat162_rn(make_float2(f1[0], f1[1]));
    u.h[3] = __float22bfloat162_rn(make_float2(f1[2], f1[3]));
    return u.v;
}

// r6 post-mortem: clean 128MB writes achieved (LDS epilogue), but dur 112->150:
// pure latency serialization (VALU 3.3%, MFMA 2.7%, HBM 17%) -- each group
// iteration stalls ~900cy on its own A-loads. r7: cross-group A prefetch --
// issue group g+4's raw f32 loads before computing group g; vmcnt FIFO
// counting turns the stall into a counted wait hidden under B-loads+MFMA.
__global__ void __launch_bounds__(256, 4) typed_linear_kernel(
        const float* __restrict__ x, const int* __restrict__ xt,
        const unsigned short* __restrict__ Wb, const float* __restrict__ bias,
        float* __restrict__ out) {
    __shared__ float s_out[4][GROUP_M * ROW_PAD];   // 4 waves x 8448 B = 33 KB
    __shared__ int s_cnt[NTYPES];
    __shared__ int s_cursor[NTYPES];
    __shared__ unsigned short s_list[ROWS_PER_BLOCK];
    __shared__ unsigned char s_gtype[MAX_GROUPS];
    __shared__ short s_gstart[MAX_GROUPS];
    __shared__ unsigned char s_gcnt[MAX_GROUPS];
    __shared__ int s_ngroups;
    __shared__ float s_bias[NTYPES * OUT_DIM];   // 4 KB

    const int tid = threadIdx.x;
    const int row0 = blockIdx.x * ROWS_PER_BLOCK;

    // ---- Phase 1: bucket this block's 256 rows by type ----
    if (tid < NTYPES) s_cnt[tid] = 0;
    __syncthreads();
    const int my_t = xt[row0 + tid];
    atomicAdd(&s_cnt[my_t], 1);
    // Stage all biases to LDS (8*128 floats = 256 float4, one per thread).
    reinterpret_cast<float4*>(s_bias)[tid] = reinterpret_cast<const float4*>(bias)[tid];
    __syncthreads();
    if (tid == 0) {
        int acc = 0, g = 0;
        for (int i = 0; i < NTYPES; ++i) {
            int c = s_cnt[i];
            s_cursor[i] = acc;
            for (int s = 0; s < c; s += GROUP_M) {
                s_gtype[g] = (unsigned char)i;
                s_gstart[g] = (short)(acc + s);
                s_gcnt[g] = (unsigned char)((c - s) < GROUP_M ? (c - s) : GROUP_M);
                ++g;
            }
            acc += c;
        }
        s_ngroups = g;
    }
    __syncthreads();
    {
        int pos = atomicAdd(&s_cursor[my_t], 1);
        s_list[pos] = (unsigned short)tid;
    }
    __syncthreads();

    // ---- Phase 2: software-pipelined per-wave MFMA over 16-row groups ----
    const int wave = tid >> 6;
    const int lane = tid & 63;
    const int m = lane & 15;     // A row / B col / C col within 16-tile
    const int q = lane >> 4;     // quad: A k-chunk = q*8.., C rows = q*4..q*4+3
    const int ngroups = s_ngroups;
    float* sow = s_out[wave];

    // Per-lane A source pointer for group gg (clamp padded rows; L1 hit).
    auto a_addr = [&](int gg) -> const float* {
        const int gs_ = s_gstart[gg];
        const int gc_ = s_gcnt[gg];
        const int mm = (m < gc_) ? m : (gc_ - 1);
        return x + (size_t)(row0 + s_list[gs_ + mm]) * IN_DIM + q * 8;
    };

    // Prologue: issue first group's raw A-loads (8 x dwordx4).
    f32x4 araw[8];
    if (wave < ngroups) {
        const float* ap = a_addr(wave);
        #pragma unroll
        for (int kc = 0; kc < 4; ++kc) {
            araw[2 * kc]     = *reinterpret_cast<const f32x4*>(ap + kc * 32);
            araw[2 * kc + 1] = *reinterpret_cast<const f32x4*>(ap + kc * 32 + 4);
        }
    }

    for (int g = wave; g < ngroups; g += 4) {
        const int t  = s_gtype[g];
        const int gs = s_gstart[g];
        const int gc = s_gcnt[g];

        // Issue NEXT group's A-loads first (fire-and-forget into anext; the
        // wait lands next iteration, hidden under this group's B+MFMA+epilogue).
        f32x4 anext[8];
        const int gn = g + 4;
        if (gn < ngroups) {
            const float* ap = a_addr(gn);
            #pragma unroll
            for (int kc = 0; kc < 4; ++kc) {
                anext[2 * kc]     = *reinterpret_cast<const f32x4*>(ap + kc * 32);
                anext[2 * kc + 1] = *reinterpret_cast<const f32x4*>(ap + kc * 32 + 4);
            }
        }

        // Convert this group's (already prefetched) A to bf16 fragments.
        bf16x8 afrag[4];
        #pragma unroll
        for (int kc = 0; kc < 4; ++kc)
            afrag[kc] = cvt_8f32_to_bf16(araw[2 * kc], araw[2 * kc + 1]);

        const unsigned short* wt = Wb + t * (IN_DIM * OUT_DIM);
        const float* sb = s_bias + t * OUT_DIM;

        // Main loop: 8 output-col tiles, acc persisted; B loads pipeline.
        f32x4 acc[8];
        #pragma unroll
        for (int nt = 0; nt < 8; ++nt) {
            const unsigned short* wcol = wt + (nt * 16 + m) * IN_DIM + q * 8;
            bf16x8 bfr[4];
            #pragma unroll
            for (int kc = 0; kc < 4; ++kc)
                bfr[kc] = *reinterpret_cast<const bf16x8*>(wcol + kc * 32);
            f32x4 a = {0.f, 0.f, 0.f, 0.f};
            #pragma unroll
            for (int kc = 0; kc < 4; ++kc)
                a = __builtin_amdgcn_mfma_f32_16x16x32_bf16(afrag[kc], bfr[kc], a, 0, 0, 0);
            acc[nt] = a;
        }

        // Epilogue A: transpose C + bias into wave-private LDS (2-way max alias).
        #pragma unroll
        for (int nt = 0; nt < 8; ++nt) {
            const float bv = sb[nt * 16 + m];
            #pragma unroll
            for (int r = 0; r < 4; ++r)
                sow[(q * 4 + r) * ROW_PAD + nt * 16 + m] = acc[nt][r] + bv;
        }

        // Epilogue B: read back row-major, store full 512B-contiguous rows.
        const int half = lane >> 5;      // 2 rows per store instruction
        const int c4 = (lane & 31) * 4;  // float col within row
        #pragma unroll
        for (int j = 0; j < 8; ++j) {
            const int rr = j * 2 + half;
            if (rr < gc) {
                const int orow = row0 + s_list[gs + rr];
                const f32x4 v = *reinterpret_cast<const f32x4*>(&sow[rr * ROW_PAD + c4]);
                *reinterpret_cast<f32x4*>(&out[(size_t)orow * OUT_DIM + c4]) = v;
            }
        }

        // Rotate prefetch registers (SSA rename; loop body not unrolled).
        #pragma unroll
        for (int i = 0; i < 8; ++i) araw[i] = anext[i];
    }
}

extern "C" void kernel_launch(void* const* d_in, const int* in_sizes, int n_in,
                              void* d_out, int out_size, void* d_ws, size_t ws_size,
                              hipStream_t stream) {
    const float* x  = (const float*)d_in[0];
    const int* xt   = (const int*)d_in[1];
    const float* W  = (const float*)d_in[2];
    const float* b  = (const float*)d_in[3];
    float* out      = (float*)d_out;
    unsigned short* Wb = (unsigned short*)d_ws;   // 8*128*128*2 = 256 KiB scratch

    prep_w_kernel<<<NTYPES * OUT_DIM, 128, 0, stream>>>(W, Wb);
    typed_linear_kernel<<<N_ROWS / ROWS_PER_BLOCK, 256, 0, stream>>>(x, xt, Wb, b, out);
}